// Round 6
// baseline (84.262 us; speedup 1.0000x reference)
//
#include <hip/hip_runtime.h>
#include <math.h>

#define DT 0.005f
#define NBLOCKS 2048
#define NTHREADS 256

typedef float fvec4 __attribute__((ext_vector_type(4)));

__device__ __forceinline__ fvec4 ntload4f(const float* p) {
    return __builtin_nontemporal_load(reinterpret_cast<const fvec4*>(p));
}
__device__ __forceinline__ float ntloadf(const float* p) {
    return __builtin_nontemporal_load(p);
}
__device__ __forceinline__ int ntloadi(const int* p) {
    return __builtin_nontemporal_load(p);
}

// ---------------- Pass A: pure streaming, no gathers ----------------
// c[i*3+k] = 0.5*dt^2*(g + rot(q, acc))[k] - tpos[i*3+k]
__global__ __launch_bounds__(NTHREADS) void pass_stream(
    const float* __restrict__ quat,
    const float* __restrict__ tpos,
    const float* __restrict__ bias,
    const float* __restrict__ batchX,
    const float* __restrict__ grav,
    const int*   __restrict__ seq_len_p,
    int B, int SF,
    float* __restrict__ c)
{
    const int S = *seq_len_p;
    const int F = SF / S;
    const int last_off = (S - 1) * F;
    const float gx = grav[0], gy = grav[1], gz = grav[2];
    const float half_dt2 = 0.5f * DT * DT;

    for (int i = blockIdx.x * blockDim.x + threadIdx.x; i < B;
         i += gridDim.x * blockDim.x) {

        fvec4 q = ntload4f(quat + (size_t)i * 4);

        const float* tp = tpos + (size_t)i * 3;
        float tpx = ntloadf(tp + 0), tpy = ntloadf(tp + 1), tpz = ntloadf(tp + 2);

        const float* bp = bias + (size_t)i * 3;
        float bx = ntloadf(bp + 0), by = ntloadf(bp + 1), bz = ntloadf(bp + 2);

        const float* xb = batchX + (size_t)i * SF + last_off;
        float ax = ntloadf(xb + 0) - bx;
        float ay = ntloadf(xb + 1) - by;
        float az = ntloadf(xb + 2) - bz;

        // quat_rotate(q, a)
        float t0 = -(q.y * ax + q.z * ay + q.w * az);
        float t1 =   q.x * ax + q.z * az - q.w * ay;
        float t2 =   q.x * ay - q.y * az + q.w * ax;
        float t3 =   q.x * az + q.y * ay - q.z * ax;
        float rx = -t0 * q.y + t1 * q.x - t2 * q.w + t3 * q.z;
        float ry = -t0 * q.z + t1 * q.w + t2 * q.x - t3 * q.y;
        float rz = -t0 * q.w - t1 * q.z + t2 * q.y + t3 * q.x;

        float* cp = c + (size_t)i * 3;
        cp[0] = half_dt2 * (gx + rx) - tpx;
        cp[1] = half_dt2 * (gy + ry) - tpy;
        cp[2] = half_dt2 * (gz + rz) - tpz;
    }
}

// ---------------- Pass B: gathers only + huber partial sums ----------------
__global__ __launch_bounds__(NTHREADS) void pass_gather(
    const float* __restrict__ pos_all,
    const float* __restrict__ vel_all,
    const int*   __restrict__ indices,
    const int*   __restrict__ seq_len_p,
    const float* __restrict__ c,
    int B,
    float* __restrict__ partials)
{
    const int S = *seq_len_p;

    float hsum = 0.f;

    for (int i = blockIdx.x * blockDim.x + threadIdx.x; i < B;
         i += gridDim.x * blockDim.x) {

        int idx = ntloadi(indices + i) - (S - 1);
        if (idx < 0) idx = 0;

        const float* pp = pos_all + (size_t)idx * 3;
        const float* vp = vel_all + (size_t)idx * 3;
        float p0x = pp[0], p0y = pp[1], p0z = pp[2];
        float v0x = vp[0], v0y = vp[1], v0z = vp[2];

        const float* cp = c + (size_t)i * 3;
        float cx = cp[0], cy = cp[1], cz = cp[2];

        float dx = p0x + v0x * DT + cx;
        float dy = p0y + v0y * DT + cy;
        float dz = p0z + v0z * DT + cz;

        float adx = fabsf(dx), ady = fabsf(dy), adz = fabsf(dz);
        hsum += (adx < 1.f) ? 0.5f * dx * dx : adx - 0.5f;
        hsum += (ady < 1.f) ? 0.5f * dy * dy : ady - 0.5f;
        hsum += (adz < 1.f) ? 0.5f * dz * dz : adz - 0.5f;
    }

    for (int off = 32; off > 0; off >>= 1)
        hsum += __shfl_down(hsum, off);

    __shared__ float wsum[NTHREADS / 64];
    int lane = threadIdx.x & 63;
    int wid  = threadIdx.x >> 6;
    if (lane == 0) wsum[wid] = hsum;
    __syncthreads();

    if (threadIdx.x == 0) {
        float s = 0.f;
        for (int w = 0; w < NTHREADS / 64; ++w) s += wsum[w];
        partials[blockIdx.x] = s;
    }
}

// ---------------- Fallback: proven single-pass kernel ----------------
__global__ __launch_bounds__(NTHREADS) void pos_loss_partial(
    const float* __restrict__ quat,
    const float* __restrict__ tpos,
    const float* __restrict__ bias,
    const float* __restrict__ batchX,
    const float* __restrict__ pos_all,
    const float* __restrict__ vel_all,
    const float* __restrict__ grav,
    const int*   __restrict__ indices,
    const int*   __restrict__ seq_len_p,
    int B, int SF,
    float* __restrict__ partials)
{
    const int S = *seq_len_p;
    const int F = SF / S;
    const int last_off = (S - 1) * F;
    const float gx = grav[0], gy = grav[1], gz = grav[2];
    const float half_dt2 = 0.5f * DT * DT;

    float hsum = 0.f;

    for (int i = blockIdx.x * blockDim.x + threadIdx.x; i < B;
         i += gridDim.x * blockDim.x) {

        int idx = ntloadi(indices + i) - (S - 1);
        if (idx < 0) idx = 0;
        const float* pp = pos_all + (size_t)idx * 3;
        const float* vp = vel_all + (size_t)idx * 3;
        float p0x = pp[0], p0y = pp[1], p0z = pp[2];
        float v0x = vp[0], v0y = vp[1], v0z = vp[2];

        fvec4 q = ntload4f(quat + (size_t)i * 4);
        const float* tp = tpos + (size_t)i * 3;
        float tpx = ntloadf(tp + 0), tpy = ntloadf(tp + 1), tpz = ntloadf(tp + 2);
        const float* bp = bias + (size_t)i * 3;
        float bx = ntloadf(bp + 0), by = ntloadf(bp + 1), bz = ntloadf(bp + 2);
        const float* xb = batchX + (size_t)i * SF + last_off;
        float ax = ntloadf(xb + 0) - bx;
        float ay = ntloadf(xb + 1) - by;
        float az = ntloadf(xb + 2) - bz;

        float t0 = -(q.y * ax + q.z * ay + q.w * az);
        float t1 =   q.x * ax + q.z * az - q.w * ay;
        float t2 =   q.x * ay - q.y * az + q.w * ax;
        float t3 =   q.x * az + q.y * ay - q.z * ax;
        float rx = -t0 * q.y + t1 * q.x - t2 * q.w + t3 * q.z;
        float ry = -t0 * q.z + t1 * q.w + t2 * q.x - t3 * q.y;
        float rz = -t0 * q.w - t1 * q.z + t2 * q.y + t3 * q.x;

        float px = p0x + v0x * DT + half_dt2 * gx + half_dt2 * rx;
        float py = p0y + v0y * DT + half_dt2 * gy + half_dt2 * ry;
        float pz = p0z + v0z * DT + half_dt2 * gz + half_dt2 * rz;

        float dx = px - tpx, dy = py - tpy, dz = pz - tpz;
        float adx = fabsf(dx), ady = fabsf(dy), adz = fabsf(dz);
        hsum += (adx < 1.f) ? 0.5f * dx * dx : adx - 0.5f;
        hsum += (ady < 1.f) ? 0.5f * dy * dy : ady - 0.5f;
        hsum += (adz < 1.f) ? 0.5f * dz * dz : adz - 0.5f;
    }

    for (int off = 32; off > 0; off >>= 1)
        hsum += __shfl_down(hsum, off);

    __shared__ float wsum[NTHREADS / 64];
    int lane = threadIdx.x & 63;
    int wid  = threadIdx.x >> 6;
    if (lane == 0) wsum[wid] = hsum;
    __syncthreads();

    if (threadIdx.x == 0) {
        float s = 0.f;
        for (int w = 0; w < NTHREADS / 64; ++w) s += wsum[w];
        partials[blockIdx.x] = s;
    }
}

__global__ __launch_bounds__(NTHREADS) void pos_loss_finish(
    const float* __restrict__ partials, int nb, float inv_cnt,
    float* __restrict__ out)
{
    float s = 0.f;
    for (int i = threadIdx.x; i < nb; i += NTHREADS) s += partials[i];

    for (int off = 32; off > 0; off >>= 1)
        s += __shfl_down(s, off);

    __shared__ float wsum[NTHREADS / 64];
    int lane = threadIdx.x & 63;
    int wid  = threadIdx.x >> 6;
    if (lane == 0) wsum[wid] = s;
    __syncthreads();

    if (threadIdx.x == 0) {
        float tot = 0.f;
        for (int w = 0; w < NTHREADS / 64; ++w) tot += wsum[w];
        out[0] = tot * inv_cnt;
    }
}

extern "C" void kernel_launch(void* const* d_in, const int* in_sizes, int n_in,
                              void* d_out, int out_size, void* d_ws, size_t ws_size,
                              hipStream_t stream) {
    const float* quat    = (const float*)d_in[0];
    const float* tpos    = (const float*)d_in[1];
    const float* bias    = (const float*)d_in[2];
    const float* batchX  = (const float*)d_in[3];
    const float* pos_all = (const float*)d_in[4];
    const float* vel_all = (const float*)d_in[5];
    const float* grav    = (const float*)d_in[6];
    const int*   indices = (const int*)d_in[7];
    const int*   seqlen  = (const int*)d_in[8];

    const int B  = in_sizes[0] / 4;
    const int SF = in_sizes[3] / B;

    float* partials = (float*)d_ws;                       // NBLOCKS floats
    float* c        = (float*)((char*)d_ws + 16384);      // B*3 floats
    const size_t need = 16384 + (size_t)B * 3 * sizeof(float);

    float inv_cnt = (float)(1.0 / (3.0 * (double)B));

    if (ws_size >= need) {
        pass_stream<<<NBLOCKS, NTHREADS, 0, stream>>>(
            quat, tpos, bias, batchX, grav, seqlen, B, SF, c);
        pass_gather<<<NBLOCKS, NTHREADS, 0, stream>>>(
            pos_all, vel_all, indices, seqlen, c, B, partials);
    } else {
        pos_loss_partial<<<NBLOCKS, NTHREADS, 0, stream>>>(
            quat, tpos, bias, batchX, pos_all, vel_all, grav, indices, seqlen,
            B, SF, partials);
    }

    pos_loss_finish<<<1, NTHREADS, 0, stream>>>(
        partials, NBLOCKS, inv_cnt, (float*)d_out);
}

// Round 7
// 74.186 us; speedup vs baseline: 1.1358x; 1.1358x over previous
//
#include <hip/hip_runtime.h>
#include <math.h>

#define DT 0.005f
#define NTHREADS 256

typedef float fvec4 __attribute__((ext_vector_type(4)));

__device__ __forceinline__ fvec4 ntload4f(const float* p) {
    return __builtin_nontemporal_load(reinterpret_cast<const fvec4*>(p));
}
__device__ __forceinline__ float ntloadf(const float* p) {
    return __builtin_nontemporal_load(p);
}
__device__ __forceinline__ int ntloadi(const int* p) {
    return __builtin_nontemporal_load(p);
}

// One element per thread: no loop-carried serialization, maximal waves.
__global__ __launch_bounds__(NTHREADS) void pos_loss_partial(
    const float* __restrict__ quat,     // B*4
    const float* __restrict__ tpos,     // B*3
    const float* __restrict__ bias,     // B*3
    const float* __restrict__ batchX,   // B*S*F
    const float* __restrict__ pos_all,  // N*3
    const float* __restrict__ vel_all,  // N*3
    const float* __restrict__ grav,     // 3
    const int*   __restrict__ indices,  // B
    const int*   __restrict__ seq_len_p,// 1
    int B, int SF,
    float* __restrict__ partials)       // gridDim.x
{
    const int S = *seq_len_p;
    const int F = SF / S;
    const int last_off = (S - 1) * F;
    const float gx = grav[0], gy = grav[1], gz = grav[2];
    const float half_dt2 = 0.5f * DT * DT;

    float hsum = 0.f;
    const int i = blockIdx.x * blockDim.x + threadIdx.x;

    if (i < B) {
        // index first (heads the longest dependency chain)
        int idx = ntloadi(indices + i) - (S - 1);
        if (idx < 0) idx = 0;
        const float* pp = pos_all + (size_t)idx * 3;
        const float* vp = vel_all + (size_t)idx * 3;
        float p0x = pp[0], p0y = pp[1], p0z = pp[2];
        float v0x = vp[0], v0y = vp[1], v0z = vp[2];

        // streaming loads (nontemporal; no reuse)
        fvec4 q = ntload4f(quat + (size_t)i * 4);
        const float* tp = tpos + (size_t)i * 3;
        float tpx = ntloadf(tp + 0), tpy = ntloadf(tp + 1), tpz = ntloadf(tp + 2);
        const float* bp = bias + (size_t)i * 3;
        float bx = ntloadf(bp + 0), by = ntloadf(bp + 1), bz = ntloadf(bp + 2);
        const float* xb = batchX + (size_t)i * SF + last_off;
        float ax = ntloadf(xb + 0) - bx;
        float ay = ntloadf(xb + 1) - by;
        float az = ntloadf(xb + 2) - bz;

        // quat_rotate(q, a): t = q * (0, a)
        float t0 = -(q.y * ax + q.z * ay + q.w * az);
        float t1 =   q.x * ax + q.z * az - q.w * ay;
        float t2 =   q.x * ay - q.y * az + q.w * ax;
        float t3 =   q.x * az + q.y * ay - q.z * ax;
        // (t * q_conj) vector part
        float rx = -t0 * q.y + t1 * q.x - t2 * q.w + t3 * q.z;
        float ry = -t0 * q.z + t1 * q.w + t2 * q.x - t3 * q.y;
        float rz = -t0 * q.w - t1 * q.z + t2 * q.y + t3 * q.x;

        float px = p0x + v0x * DT + half_dt2 * gx + half_dt2 * rx;
        float py = p0y + v0y * DT + half_dt2 * gy + half_dt2 * ry;
        float pz = p0z + v0z * DT + half_dt2 * gz + half_dt2 * rz;

        float dx = px - tpx, dy = py - tpy, dz = pz - tpz;
        float adx = fabsf(dx), ady = fabsf(dy), adz = fabsf(dz);
        hsum += (adx < 1.f) ? 0.5f * dx * dx : adx - 0.5f;
        hsum += (ady < 1.f) ? 0.5f * dy * dy : ady - 0.5f;
        hsum += (adz < 1.f) ? 0.5f * dz * dz : adz - 0.5f;
    }

    // wave-64 reduce
    for (int off = 32; off > 0; off >>= 1)
        hsum += __shfl_down(hsum, off);

    __shared__ float wsum[NTHREADS / 64];
    int lane = threadIdx.x & 63;
    int wid  = threadIdx.x >> 6;
    if (lane == 0) wsum[wid] = hsum;
    __syncthreads();

    if (threadIdx.x == 0) {
        float s = 0.f;
        for (int w = 0; w < NTHREADS / 64; ++w) s += wsum[w];
        partials[blockIdx.x] = s;
    }
}

__global__ __launch_bounds__(NTHREADS) void pos_loss_finish(
    const float* __restrict__ partials, int nb, float inv_cnt,
    float* __restrict__ out)
{
    float s = 0.f;
    for (int i = threadIdx.x; i < nb; i += NTHREADS) s += partials[i];

    for (int off = 32; off > 0; off >>= 1)
        s += __shfl_down(s, off);

    __shared__ float wsum[NTHREADS / 64];
    int lane = threadIdx.x & 63;
    int wid  = threadIdx.x >> 6;
    if (lane == 0) wsum[wid] = s;
    __syncthreads();

    if (threadIdx.x == 0) {
        float tot = 0.f;
        for (int w = 0; w < NTHREADS / 64; ++w) tot += wsum[w];
        out[0] = tot * inv_cnt;
    }
}

extern "C" void kernel_launch(void* const* d_in, const int* in_sizes, int n_in,
                              void* d_out, int out_size, void* d_ws, size_t ws_size,
                              hipStream_t stream) {
    const float* quat    = (const float*)d_in[0];
    const float* tpos    = (const float*)d_in[1];
    const float* bias    = (const float*)d_in[2];
    const float* batchX  = (const float*)d_in[3];
    const float* pos_all = (const float*)d_in[4];
    const float* vel_all = (const float*)d_in[5];
    const float* grav    = (const float*)d_in[6];
    const int*   indices = (const int*)d_in[7];
    const int*   seqlen  = (const int*)d_in[8];

    const int B  = in_sizes[0] / 4;
    const int SF = in_sizes[3] / B;

    float* partials = (float*)d_ws;
    float inv_cnt = (float)(1.0 / (3.0 * (double)B));

    const int nblocks = (B + NTHREADS - 1) / NTHREADS;   // 4096 for B=1M

    pos_loss_partial<<<nblocks, NTHREADS, 0, stream>>>(
        quat, tpos, bias, batchX, pos_all, vel_all, grav, indices, seqlen,
        B, SF, partials);

    pos_loss_finish<<<1, NTHREADS, 0, stream>>>(
        partials, nblocks, inv_cnt, (float*)d_out);
}

// Round 8
// 71.654 us; speedup vs baseline: 1.1760x; 1.0353x over previous
//
#include <hip/hip_runtime.h>
#include <math.h>

#define DT 0.005f
#define NBLOCKS 2048
#define NTHREADS 256

typedef float fvec4 __attribute__((ext_vector_type(4)));

__device__ __forceinline__ fvec4 ntload4f(const float* p) {
    return __builtin_nontemporal_load(reinterpret_cast<const fvec4*>(p));
}
__device__ __forceinline__ float ntloadf(const float* p) {
    return __builtin_nontemporal_load(p);
}
__device__ __forceinline__ int ntloadi(const int* p) {
    return __builtin_nontemporal_load(p);
}

// ---------- Prep: w = pos_all + DT * vel_all (pure streaming, elementwise) ----------
__global__ __launch_bounds__(NTHREADS) void prep_w(
    const float* __restrict__ pos_all,
    const float* __restrict__ vel_all,
    float* __restrict__ w,
    int n_flat)                      // 3*N floats
{
    const int nv = n_flat >> 2;
    const int stride = gridDim.x * blockDim.x;

    for (int c = blockIdx.x * blockDim.x + threadIdx.x; c < nv; c += stride) {
        fvec4 p = ntload4f(pos_all + (size_t)c * 4);
        fvec4 v = ntload4f(vel_all + (size_t)c * 4);
        fvec4 r;
        r.x = p.x + DT * v.x;
        r.y = p.y + DT * v.y;
        r.z = p.z + DT * v.z;
        r.w = p.w + DT * v.w;
        // plain store: we WANT w cached (it is gathered next kernel)
        *reinterpret_cast<fvec4*>(w + (size_t)c * 4) = r;
    }
    // tail
    for (int j = (nv << 2) + blockIdx.x * blockDim.x + threadIdx.x; j < n_flat;
         j += stride)
        w[j] = pos_all[j] + DT * vel_all[j];
}

// ---------- Main: streams + ONE random gather per element ----------
__global__ __launch_bounds__(NTHREADS) void pos_loss_partial_w(
    const float* __restrict__ quat,     // B*4
    const float* __restrict__ tpos,     // B*3
    const float* __restrict__ bias,     // B*3
    const float* __restrict__ batchX,   // B*S*F
    const float* __restrict__ w,        // N*3  (pos + DT*vel)
    const float* __restrict__ grav,     // 3
    const int*   __restrict__ indices,  // B
    const int*   __restrict__ seq_len_p,// 1
    int B, int SF,
    float* __restrict__ partials)       // NBLOCKS
{
    const int S = *seq_len_p;
    const int F = SF / S;
    const int last_off = (S - 1) * F;
    const float gx = grav[0], gy = grav[1], gz = grav[2];
    const float half_dt2 = 0.5f * DT * DT;

    float hsum = 0.f;

    for (int i = blockIdx.x * blockDim.x + threadIdx.x; i < B;
         i += gridDim.x * blockDim.x) {

        // index first (heads the longest dependency chain), single gather
        int idx = ntloadi(indices + i) - (S - 1);
        if (idx < 0) idx = 0;
        const float* wp = w + (size_t)idx * 3;
        float w0 = wp[0], w1 = wp[1], w2 = wp[2];

        // streaming loads: nontemporal
        fvec4 q = ntload4f(quat + (size_t)i * 4);
        const float* tp = tpos + (size_t)i * 3;
        float tpx = ntloadf(tp + 0), tpy = ntloadf(tp + 1), tpz = ntloadf(tp + 2);
        const float* bp = bias + (size_t)i * 3;
        float bx = ntloadf(bp + 0), by = ntloadf(bp + 1), bz = ntloadf(bp + 2);
        const float* xb = batchX + (size_t)i * SF + last_off;
        float ax = ntloadf(xb + 0) - bx;
        float ay = ntloadf(xb + 1) - by;
        float az = ntloadf(xb + 2) - bz;

        // quat_rotate(q, a): t = q * (0, a)
        float t0 = -(q.y * ax + q.z * ay + q.w * az);
        float t1 =   q.x * ax + q.z * az - q.w * ay;
        float t2 =   q.x * ay - q.y * az + q.w * ax;
        float t3 =   q.x * az + q.y * ay - q.z * ax;
        // (t * q_conj) vector part
        float rx = -t0 * q.y + t1 * q.x - t2 * q.w + t3 * q.z;
        float ry = -t0 * q.z + t1 * q.w + t2 * q.x - t3 * q.y;
        float rz = -t0 * q.w - t1 * q.z + t2 * q.y + t3 * q.x;

        // pred = w + 0.5*g*dt^2 + 0.5*rot*dt^2   (w = p0 + v0*DT)
        float px = w0 + half_dt2 * gx + half_dt2 * rx;
        float py = w1 + half_dt2 * gy + half_dt2 * ry;
        float pz = w2 + half_dt2 * gz + half_dt2 * rz;

        float dx = px - tpx, dy = py - tpy, dz = pz - tpz;
        float adx = fabsf(dx), ady = fabsf(dy), adz = fabsf(dz);
        hsum += (adx < 1.f) ? 0.5f * dx * dx : adx - 0.5f;
        hsum += (ady < 1.f) ? 0.5f * dy * dy : ady - 0.5f;
        hsum += (adz < 1.f) ? 0.5f * dz * dz : adz - 0.5f;
    }

    for (int off = 32; off > 0; off >>= 1)
        hsum += __shfl_down(hsum, off);

    __shared__ float wsum[NTHREADS / 64];
    int lane = threadIdx.x & 63;
    int wid  = threadIdx.x >> 6;
    if (lane == 0) wsum[wid] = hsum;
    __syncthreads();

    if (threadIdx.x == 0) {
        float s = 0.f;
        for (int wv = 0; wv < NTHREADS / 64; ++wv) s += wsum[wv];
        partials[blockIdx.x] = s;
    }
}

// ---------- Fallback: proven round-5 single-pass ----------
__global__ __launch_bounds__(NTHREADS) void pos_loss_partial(
    const float* __restrict__ quat,
    const float* __restrict__ tpos,
    const float* __restrict__ bias,
    const float* __restrict__ batchX,
    const float* __restrict__ pos_all,
    const float* __restrict__ vel_all,
    const float* __restrict__ grav,
    const int*   __restrict__ indices,
    const int*   __restrict__ seq_len_p,
    int B, int SF,
    float* __restrict__ partials)
{
    const int S = *seq_len_p;
    const int F = SF / S;
    const int last_off = (S - 1) * F;
    const float gx = grav[0], gy = grav[1], gz = grav[2];
    const float half_dt2 = 0.5f * DT * DT;

    float hsum = 0.f;

    for (int i = blockIdx.x * blockDim.x + threadIdx.x; i < B;
         i += gridDim.x * blockDim.x) {

        int idx = ntloadi(indices + i) - (S - 1);
        if (idx < 0) idx = 0;
        const float* pp = pos_all + (size_t)idx * 3;
        const float* vp = vel_all + (size_t)idx * 3;
        float p0x = pp[0], p0y = pp[1], p0z = pp[2];
        float v0x = vp[0], v0y = vp[1], v0z = vp[2];

        fvec4 q = ntload4f(quat + (size_t)i * 4);
        const float* tp = tpos + (size_t)i * 3;
        float tpx = ntloadf(tp + 0), tpy = ntloadf(tp + 1), tpz = ntloadf(tp + 2);
        const float* bp = bias + (size_t)i * 3;
        float bx = ntloadf(bp + 0), by = ntloadf(bp + 1), bz = ntloadf(bp + 2);
        const float* xb = batchX + (size_t)i * SF + last_off;
        float ax = ntloadf(xb + 0) - bx;
        float ay = ntloadf(xb + 1) - by;
        float az = ntloadf(xb + 2) - bz;

        float t0 = -(q.y * ax + q.z * ay + q.w * az);
        float t1 =   q.x * ax + q.z * az - q.w * ay;
        float t2 =   q.x * ay - q.y * az + q.w * ax;
        float t3 =   q.x * az + q.y * ay - q.z * ax;
        float rx = -t0 * q.y + t1 * q.x - t2 * q.w + t3 * q.z;
        float ry = -t0 * q.z + t1 * q.w + t2 * q.x - t3 * q.y;
        float rz = -t0 * q.w - t1 * q.z + t2 * q.y + t3 * q.x;

        float px = p0x + v0x * DT + half_dt2 * gx + half_dt2 * rx;
        float py = p0y + v0y * DT + half_dt2 * gy + half_dt2 * ry;
        float pz = p0z + v0z * DT + half_dt2 * gz + half_dt2 * rz;

        float dx = px - tpx, dy = py - tpy, dz = pz - tpz;
        float adx = fabsf(dx), ady = fabsf(dy), adz = fabsf(dz);
        hsum += (adx < 1.f) ? 0.5f * dx * dx : adx - 0.5f;
        hsum += (ady < 1.f) ? 0.5f * dy * dy : ady - 0.5f;
        hsum += (adz < 1.f) ? 0.5f * dz * dz : adz - 0.5f;
    }

    for (int off = 32; off > 0; off >>= 1)
        hsum += __shfl_down(hsum, off);

    __shared__ float wsum[NTHREADS / 64];
    int lane = threadIdx.x & 63;
    int wid  = threadIdx.x >> 6;
    if (lane == 0) wsum[wid] = hsum;
    __syncthreads();

    if (threadIdx.x == 0) {
        float s = 0.f;
        for (int wv = 0; wv < NTHREADS / 64; ++wv) s += wsum[wv];
        partials[blockIdx.x] = s;
    }
}

__global__ __launch_bounds__(NTHREADS) void pos_loss_finish(
    const float* __restrict__ partials, int nb, float inv_cnt,
    float* __restrict__ out)
{
    float s = 0.f;
    for (int i = threadIdx.x; i < nb; i += NTHREADS) s += partials[i];

    for (int off = 32; off > 0; off >>= 1)
        s += __shfl_down(s, off);

    __shared__ float wsum[NTHREADS / 64];
    int lane = threadIdx.x & 63;
    int wid  = threadIdx.x >> 6;
    if (lane == 0) wsum[wid] = s;
    __syncthreads();

    if (threadIdx.x == 0) {
        float tot = 0.f;
        for (int w = 0; w < NTHREADS / 64; ++w) tot += wsum[w];
        out[0] = tot * inv_cnt;
    }
}

extern "C" void kernel_launch(void* const* d_in, const int* in_sizes, int n_in,
                              void* d_out, int out_size, void* d_ws, size_t ws_size,
                              hipStream_t stream) {
    const float* quat    = (const float*)d_in[0];
    const float* tpos    = (const float*)d_in[1];
    const float* bias    = (const float*)d_in[2];
    const float* batchX  = (const float*)d_in[3];
    const float* pos_all = (const float*)d_in[4];
    const float* vel_all = (const float*)d_in[5];
    const float* grav    = (const float*)d_in[6];
    const int*   indices = (const int*)d_in[7];
    const int*   seqlen  = (const int*)d_in[8];

    const int B      = in_sizes[0] / 4;
    const int SF     = in_sizes[3] / B;
    const int n_flat = in_sizes[4];          // 3*N

    float* partials = (float*)d_ws;
    float* w        = (float*)((char*)d_ws + 16384);
    const size_t need = 16384 + (size_t)n_flat * sizeof(float);

    float inv_cnt = (float)(1.0 / (3.0 * (double)B));

    if (ws_size >= need) {
        prep_w<<<1536, NTHREADS, 0, stream>>>(pos_all, vel_all, w, n_flat);
        pos_loss_partial_w<<<NBLOCKS, NTHREADS, 0, stream>>>(
            quat, tpos, bias, batchX, w, grav, indices, seqlen,
            B, SF, partials);
    } else {
        pos_loss_partial<<<NBLOCKS, NTHREADS, 0, stream>>>(
            quat, tpos, bias, batchX, pos_all, vel_all, grav, indices, seqlen,
            B, SF, partials);
    }

    pos_loss_finish<<<1, NTHREADS, 0, stream>>>(
        partials, NBLOCKS, inv_cnt, (float*)d_out);
}